// Round 7
// baseline (301.814 us; speedup 1.0000x reference)
//
#include <hip/hip_runtime.h>

#define RAYS 65536
#define NS   192
#define GPB  4                      // ray-groups (of 8 rays) per block
#define T_BYTES 6176                // 8*193*4
#define S_BYTES 6144                // 8*192*4
#define C_BYTES 18432               // 8*192*3*4

__device__ __forceinline__ int   f2i(float x){ return __builtin_bit_cast(int, x); }
__device__ __forceinline__ float i2f(int x)  { return __builtin_bit_cast(float, x); }

// v_mov_b32_dpp with old=0, bound_ctrl:0 (invalid lanes -> 0)
template<int CTRL, int ROWMASK>
__device__ __forceinline__ float dpp0(float x){
    return i2f(__builtin_amdgcn_update_dpp(0, f2i(x), CTRL, ROWMASK, 0xF, true));
}
template<int OFF>
__device__ __forceinline__ float swz(float x){
    return i2f(__builtin_amdgcn_ds_swizzle(f2i(x), OFF));
}

// partner value at sub-lane XOR distance JL (within each 32-lane half)
template<int JL>
__device__ __forceinline__ float partner(float x){
    if      constexpr (JL == 1)  return dpp0<0xB1, 0xF>(x);   // quad_perm xor1
    else if constexpr (JL == 2)  return dpp0<0x4E, 0xF>(x);   // quad_perm xor2
    else if constexpr (JL == 3)  return dpp0<0x1B, 0xF>(x);   // quad_perm [3,2,1,0] = xor3
    else if constexpr (JL == 4)  return swz<0x101F>(x);       // xor4
    else if constexpr (JL == 7)  return swz<0x1C1F>(x);       // xor7
    else if constexpr (JL == 8)  return swz<0x201F>(x);       // xor8
    else if constexpr (JL == 15) return swz<0x3C1F>(x);       // xor15
    else if constexpr (JL == 16) return swz<0x401F>(x);       // xor16
    else                         return swz<0x7C1F>(x);       // xor31
}

// ascending in-lane compare-exchange: 2 VALU (fmin+fmax)
__device__ __forceinline__ void ce(float &a, float &b){
    float mn = fminf(a, b), mx = fmaxf(a, b);
    a = mn; b = mx;
}

// normalized cross-lane halver phase at lane distance JL; 'lower' = ((sl&JL)==0).
template<int JL>
__device__ __forceinline__ void xphase(float v[8], bool lower){
    #pragma unroll
    for (int r = 0; r < 8; ++r){
        float p = partner<JL>(v[r]);
        v[r] = ((v[r] < p) == lower) ? v[r] : p;
    }
}

// mirror phase opening a merge of two ascending runs: (sl, r) pairs with (sl^JL, 7-r).
template<int JL>
__device__ __forceinline__ void xmirror(float v[8], bool lower){
    #pragma unroll
    for (int r = 0; r < 4; ++r){
        float pa = partner<JL>(v[7 - r]);
        float pb = partner<JL>(v[r]);
        v[r]     = ((v[r]     < pa) == lower) ? v[r]     : pa;
        v[7 - r] = ((v[7 - r] < pb) == lower) ? v[7 - r] : pb;
    }
}

// in-lane bitonic cleanup (strides 4,2,1), ascending
__device__ __forceinline__ void rmerge(float v[8]){
    ce(v[0],v[4]); ce(v[1],v[5]); ce(v[2],v[6]); ce(v[3],v[7]);
    ce(v[0],v[2]); ce(v[1],v[3]); ce(v[4],v[6]); ce(v[5],v[7]);
    ce(v[0],v[1]); ce(v[2],v[3]); ce(v[4],v[5]); ce(v[6],v[7]);
}

// Batcher odd-even 8-sorter, 19 CEs, ascending
__device__ __forceinline__ void sort8(float v[8]){
    ce(v[0],v[1]); ce(v[2],v[3]); ce(v[4],v[5]); ce(v[6],v[7]);
    ce(v[0],v[2]); ce(v[1],v[3]); ce(v[4],v[6]); ce(v[5],v[7]);
    ce(v[1],v[2]); ce(v[5],v[6]);
    ce(v[0],v[4]); ce(v[1],v[5]); ce(v[2],v[6]); ce(v[3],v[7]);
    ce(v[2],v[4]); ce(v[3],v[5]);
    ce(v[1],v[2]); ce(v[3],v[4]); ce(v[5],v[6]);
}

// 32-lane butterfly sum (both halves independently)
__device__ __forceinline__ float halfsum(float a){
    a += dpp0<0xB1, 0xF>(a);
    a += dpp0<0x4E, 0xF>(a);
    a += swz<0x101F>(a);
    a += swz<0x201F>(a);
    a += swz<0x401F>(a);
    return a;
}

// ---- async global -> LDS (DMA), 16B per lane, wave-uniform LDS base ----
__device__ __forceinline__ void stage16(const void* g, void* l){
    __builtin_amdgcn_global_load_lds(
        (const __attribute__((address_space(1))) void*)g,
        (__attribute__((address_space(3))) void*)l, 16, 0, 0);
}

// stage t (6176B -> 8KB region) + sigma (6144B -> 8KB region at +8192)
// All rounds full-wave; tail lanes clamp the GLOBAL address (duplicate reads
// land in the never-read LDS pad), so issue counts stay wave-uniform.
__device__ __forceinline__ void stage_ts(const char* tb, const char* sb,
                                         char* buf, int tid){
    char* ldw = buf + (tid >> 6) * 1024;       // wave-uniform base per round
    const int o0 = tid * 16;
    stage16(tb + o0, ldw);                                        // t [0,4096)
    int o1 = 4096 + o0; if (o1 > T_BYTES - 16) o1 = T_BYTES - 16;
    stage16(tb + o1, ldw + 4096);                                 // t [4096,..)
    stage16(sb + o0, ldw + 8192);                                 // s [0,4096)
    int o2 = 4096 + o0; if (o2 > S_BYTES - 16) o2 = S_BYTES - 16;
    stage16(sb + o2, ldw + 12288);                                // s [4096,..)
}

// stage c (18432B -> 20KB region), 5 rounds
__device__ __forceinline__ void stage_c(const char* cb, char* buf, int tid){
    char* ldw = buf + (tid >> 6) * 1024;
    const int o = tid * 16;
    stage16(cb + o,         ldw);
    stage16(cb + o + 4096,  ldw + 4096);
    stage16(cb + o + 8192,  ldw + 8192);
    stage16(cb + o + 12288, ldw + 12288);
    int o4 = o + 16384; if (o4 > C_BYTES - 16) o4 = C_BYTES - 16;
    stage16(cb + o4,        ldw + 16384);
}

__global__ __launch_bounds__(256, 3) void nerf_integrate(
    const float* __restrict__ t,
    const float* __restrict__ sigma,
    const float* __restrict__ c,
    float* __restrict__ out)
{
    // 2x16KB t+sigma double buffer + 20KB c single buffer = 53248 B -> 3 blocks/CU
    __shared__ __align__(16) char ts_lds[2][16384];
    __shared__ __align__(16) char c_lds[20480];

    const int tid   = threadIdx.x;
    const int lane  = tid & 63;
    const int sl    = tid & 31;     // sub-lane within the ray's 32 lanes
    const int rl    = tid >> 5;     // ray-local index 0..7 within group
    const int gbase = blockIdx.x * GPB;

    const bool lo1  = (sl & 1)  == 0;
    const bool lo2  = (sl & 2)  == 0;
    const bool lo4  = (sl & 4)  == 0;
    const bool lo8  = (sl & 8)  == 0;
    const bool lo16 = (sl & 16) == 0;
    const bool act  = (sl < 24);
    const int  sls  = act ? sl : 0;

    // prologue: stage t+sigma for the first group into buffer 0
    stage_ts((const char*)t     + (size_t)gbase * T_BYTES,
             (const char*)sigma + (size_t)gbase * S_BYTES, ts_lds[0], tid);

    int cur = 0;
    for (int i = 0; i < GPB; ++i){
        const int g   = gbase + i;
        const int gn  = (i + 1 < GPB) ? (g + 1) : g;   // re-stage last (uniform)
        const int ray = g * 8 + rl;

        // barrier: prev iteration's loads drained (compiler emits vmcnt(0));
        // safe to read ts_lds[cur] and overwrite c_lds / ts_lds[cur^1].
        __syncthreads();

        // ---- t & sigma for group g from LDS into registers (before stages) ----
        const float* tl = (const float*)ts_lds[cur] + rl * 193;
        float v[8];
        #pragma unroll
        for (int j = 0; j < 6; ++j) v[j] = tl[32 * j + sl];
        float t192 = tl[192];
        const float* srow = (const float*)(ts_lds[cur] + 8192) + rl * NS + 8 * sls;
        float4 s0 = *reinterpret_cast<const float4*>(srow);
        float4 s1 = *reinterpret_cast<const float4*>(srow + 4);

        // ---- issue async stages: c(g) now, t+sigma(g+1) into other buffer ----
        stage_c((const char*)c + (size_t)g * C_BYTES, c_lds, tid);
        stage_ts((const char*)t     + (size_t)gn * T_BYTES,
                 (const char*)sigma + (size_t)gn * S_BYTES, ts_lds[cur ^ 1], tid);
        __builtin_amdgcn_sched_barrier(0);   // pin stage issue above the sort

        v[6] = (sl == 0) ? t192 : 1e30f;
        v[7] = 1e30f;

        // ==== mirror-normalized bitonic sort of 256: bits [2:0]=r, [7:3]=sl ====
        sort8(v);
        xmirror<1>(v, lo1);
        rmerge(v);
        xmirror<3>(v, lo2);
        xphase<1>(v, lo1);
        rmerge(v);
        xmirror<7>(v, lo4);
        xphase<2>(v, lo2);
        xphase<1>(v, lo1);
        rmerge(v);
        xmirror<15>(v, lo8);
        xphase<4>(v, lo4);
        xphase<2>(v, lo2);
        xphase<1>(v, lo1);
        rmerge(v);
        xmirror<31>(v, lo16);
        xphase<8>(v, lo8);
        xphase<4>(v, lo4);
        xphase<2>(v, lo2);
        xphase<1>(v, lo1);
        rmerge(v);

        // ---- neighbor for r=7 ----
        float nxt = __shfl(v[0], lane + 1, 64);   // lane31/63 pads -> don't care

        // ---- sdt ----
        float sg8[8] = { s0.x, s0.y, s0.z, s0.w, s1.x, s1.y, s1.z, s1.w };
        float sdt[8];
        #pragma unroll
        for (int r = 0; r < 8; ++r){
            float tn = (r < 7) ? v[r + 1] : nxt;
            sdt[r] = act ? sg8[r] * (tn - v[r]) : 0.0f;
        }

        // ---- prefix sum: in-lane inclusive over 8, then per-half DPP scan ----
        float pre[8];
        float run = 0.0f;
        #pragma unroll
        for (int r = 0; r < 8; ++r){ run += sdt[r]; pre[r] = run; }
        float x = run;
        x += dpp0<0x111, 0xF>(x);   // row_shr:1
        x += dpp0<0x112, 0xF>(x);   // row_shr:2
        x += dpp0<0x114, 0xF>(x);   // row_shr:4
        x += dpp0<0x118, 0xF>(x);   // row_shr:8
        x += dpp0<0x142, 0xA>(x);   // row_bcast:15 into rows 1,3 (per-half scan)
        float laneExcl = x - run;

        // ---- wi via telescoped exponentials (9 exps) ----
        float wi[8];
        float prev = __expf(-laneExcl);
        #pragma unroll
        for (int r = 0; r < 8; ++r){
            float e = __expf(-(laneExcl + pre[r]));
            wi[r] = prev - e;
            prev = e;
        }
        if (act){
            float* wrow = out + (size_t)RAYS * 3 + (size_t)ray * NS + 8 * sl;
            *reinterpret_cast<float4*>(wrow)     = make_float4(wi[0], wi[1], wi[2], wi[3]);
            *reinterpret_cast<float4*>(wrow + 4) = make_float4(wi[4], wi[5], wi[6], wi[7]);
        }

        // barrier: each wave drained its own c-stage loads (vmcnt(0) at barrier),
        // and all waves passed -> c(g) fully visible in LDS.
        __syncthreads();

        // ---- rgb from LDS c, per-half reduce (wi==0 kills clamped lanes) ----
        const float* crow = (const float*)c_lds + rl * (NS * 3) + 24 * sls;
        float a0 = 0.f, a1 = 0.f, a2 = 0.f;
        #pragma unroll
        for (int m = 0; m < 6; ++m){
            float4 cc = *reinterpret_cast<const float4*>(crow + 4 * m);
            #pragma unroll
            for (int j = 0; j < 4; ++j){
                float e = (j == 0) ? cc.x : (j == 1) ? cc.y : (j == 2) ? cc.z : cc.w;
                int k  = 4 * m + j;
                int rr = k / 3, ch = k % 3;      // compile-time after unroll
                if      (ch == 0) a0 += wi[rr] * e;
                else if (ch == 1) a1 += wi[rr] * e;
                else              a2 += wi[rr] * e;
            }
        }
        a0 = halfsum(a0);
        a1 = halfsum(a1);
        a2 = halfsum(a2);
        if (sl < 3){
            float val = (sl == 0) ? a0 : ((sl == 1) ? a1 : a2);
            out[(size_t)ray * 3 + sl] = val;
        }

        cur ^= 1;
    }
}

extern "C" void kernel_launch(void* const* d_in, const int* in_sizes, int n_in,
                              void* d_out, int out_size, void* d_ws, size_t ws_size,
                              hipStream_t stream) {
    const float* t     = (const float*)d_in[0];
    const float* sigma = (const float*)d_in[1];
    const float* c     = (const float*)d_in[2];
    float* out = (float*)d_out;
    nerf_integrate<<<RAYS / 8 / GPB, 256, 0, stream>>>(t, sigma, c, out);
}

// Round 8
// 290.972 us; speedup vs baseline: 1.0373x; 1.0373x over previous
//
#include <hip/hip_runtime.h>

#define RAYS 65536
#define NS   192

__device__ __forceinline__ int   f2i(float x){ return __builtin_bit_cast(int, x); }
__device__ __forceinline__ float i2f(int x)  { return __builtin_bit_cast(float, x); }

// v_mov_b32_dpp with old=0, bound_ctrl:0 (invalid lanes -> 0); all sources used
// here are valid within-row lanes, so 'old' is never consumed.
template<int CTRL, int ROWMASK>
__device__ __forceinline__ float dpp0(float x){
    return i2f(__builtin_amdgcn_update_dpp(0, f2i(x), CTRL, ROWMASK, 0xF, true));
}
template<int OFF>
__device__ __forceinline__ float swz(float x){
    return i2f(__builtin_amdgcn_ds_swizzle(f2i(x), OFF));
}

// partner value at sub-lane XOR distance JL (within each 32-lane half).
// DPP (VALU pipe, no lgkmcnt) everywhere except xor16/xor31:
//   xor1/2/3: quad_perm; xor7: row_half_mirror; xor15: row_mirror;
//   xor8: row_ror:8 ((l+8)%16 == l^8); xor4: xor3 then xor7 (3^7=4).
template<int JL>
__device__ __forceinline__ float partner(float x){
    if      constexpr (JL == 1)  return dpp0<0xB1,  0xF>(x);                    // quad_perm [1,0,3,2]
    else if constexpr (JL == 2)  return dpp0<0x4E,  0xF>(x);                    // quad_perm [2,3,0,1]
    else if constexpr (JL == 3)  return dpp0<0x1B,  0xF>(x);                    // quad_perm [3,2,1,0]
    else if constexpr (JL == 4)  return dpp0<0x141, 0xF>(dpp0<0x1B, 0xF>(x));   // xor7(xor3(x))
    else if constexpr (JL == 7)  return dpp0<0x141, 0xF>(x);                    // row_half_mirror
    else if constexpr (JL == 8)  return dpp0<0x128, 0xF>(x);                    // row_ror:8
    else if constexpr (JL == 15) return dpp0<0x140, 0xF>(x);                    // row_mirror
    else if constexpr (JL == 16) return swz<0x401F>(x);                         // xor16 (LDS pipe)
    else                         return swz<0x7C1F>(x);                         // xor31 (LDS pipe)
}

// ascending in-lane compare-exchange: 2 VALU (fmin+fmax)
__device__ __forceinline__ void ce(float &a, float &b){
    float mn = fminf(a, b), mx = fmaxf(a, b);
    a = mn; b = mx;
}

// normalized cross-lane halver phase at lane distance JL; 'lower' = ((sl&JL)==0).
template<int JL>
__device__ __forceinline__ void xphase(float v[8], bool lower){
    #pragma unroll
    for (int r = 0; r < 8; ++r){
        float p = partner<JL>(v[r]);
        v[r] = ((v[r] < p) == lower) ? v[r] : p;
    }
}

// mirror phase opening a merge of two ascending runs: (sl, r) pairs with (sl^JL, 7-r).
template<int JL>
__device__ __forceinline__ void xmirror(float v[8], bool lower){
    #pragma unroll
    for (int r = 0; r < 4; ++r){
        float pa = partner<JL>(v[7 - r]);
        float pb = partner<JL>(v[r]);
        v[r]     = ((v[r]     < pa) == lower) ? v[r]     : pa;
        v[7 - r] = ((v[7 - r] < pb) == lower) ? v[7 - r] : pb;
    }
}

// in-lane bitonic cleanup (strides 4,2,1), ascending
__device__ __forceinline__ void rmerge(float v[8]){
    ce(v[0],v[4]); ce(v[1],v[5]); ce(v[2],v[6]); ce(v[3],v[7]);
    ce(v[0],v[2]); ce(v[1],v[3]); ce(v[4],v[6]); ce(v[5],v[7]);
    ce(v[0],v[1]); ce(v[2],v[3]); ce(v[4],v[5]); ce(v[6],v[7]);
}

// Batcher odd-even 8-sorter, 19 CEs, ascending
__device__ __forceinline__ void sort8(float v[8]){
    ce(v[0],v[1]); ce(v[2],v[3]); ce(v[4],v[5]); ce(v[6],v[7]);
    ce(v[0],v[2]); ce(v[1],v[3]); ce(v[4],v[6]); ce(v[5],v[7]);
    ce(v[1],v[2]); ce(v[5],v[6]);
    ce(v[0],v[4]); ce(v[1],v[5]); ce(v[2],v[6]); ce(v[3],v[7]);
    ce(v[2],v[4]); ce(v[3],v[5]);
    ce(v[1],v[2]); ce(v[3],v[4]); ce(v[5],v[6]);
}

// 32-lane butterfly sum, masks {1,2,7,8,16} (linearly independent over GF(2):
// span = all 5 bits -> full 32-lane reduce). Only the last step uses LDS.
__device__ __forceinline__ float halfsum(float a){
    a += dpp0<0xB1,  0xF>(a);   // xor1
    a += dpp0<0x4E,  0xF>(a);   // xor2
    a += dpp0<0x141, 0xF>(a);   // xor7
    a += dpp0<0x128, 0xF>(a);   // xor8
    a += swz<0x401F>(a);        // xor16
    return a;
}

__global__ __launch_bounds__(256) void nerf_integrate(
    const float* __restrict__ t,
    const float* __restrict__ sigma,
    const float* __restrict__ c,
    float* __restrict__ out)
{
    const int tid  = threadIdx.x;
    const int lane = tid & 63;
    const int sl   = tid & 31;                     // sub-lane within the ray's 32 lanes
    const int ray  = blockIdx.x * 8 + (tid >> 5);  // 2 rays per wave, 8 per block

    const bool lo1  = (sl & 1)  == 0;
    const bool lo2  = (sl & 2)  == 0;
    const bool lo4  = (sl & 4)  == 0;
    const bool lo8  = (sl & 8)  == 0;
    const bool lo16 = (sl & 16) == 0;

    const bool act = (sl < 24);                    // lane's 8 elements all < 192
    const int  sls = act ? sl : 0;                 // clamped: inactive lanes read row start

    // ---- t: coalesced (placement irrelevant pre-sort) ----
    const float* trow = t + (size_t)ray * 193;
    float v[8];
    #pragma unroll
    for (int j = 0; j < 6; ++j) v[j] = trow[32 * j + sl];
    float t192 = trow[192];
    v[6] = (sl == 0) ? t192 : 1e30f;
    v[7] = 1e30f;

    // ---- sigma & c (addresses sort-independent) ----
    const float* srow = sigma + (size_t)ray * NS + 8 * sls;
    float4 s0 = *reinterpret_cast<const float4*>(srow);
    float4 s1 = *reinterpret_cast<const float4*>(srow + 4);

    const float* crow = c + (size_t)ray * (NS * 3) + 24 * sls;
    float4 c0 = *reinterpret_cast<const float4*>(crow);
    float4 c1 = *reinterpret_cast<const float4*>(crow + 4);
    float4 c2 = *reinterpret_cast<const float4*>(crow + 8);
    float4 c3 = *reinterpret_cast<const float4*>(crow + 12);
    float4 c4 = *reinterpret_cast<const float4*>(crow + 16);
    float4 c5 = *reinterpret_cast<const float4*>(crow + 20);

    // ==== mirror-normalized bitonic sort of 256: bits [2:0]=r, [7:3]=sl ====
    sort8(v);
    // merge to 16
    xmirror<1>(v, lo1);
    rmerge(v);
    // merge to 32
    xmirror<3>(v, lo2);
    xphase<1>(v, lo1);
    rmerge(v);
    // merge to 64
    xmirror<7>(v, lo4);
    xphase<2>(v, lo2);
    xphase<1>(v, lo1);
    rmerge(v);
    // merge to 128
    xmirror<15>(v, lo8);
    xphase<4>(v, lo4);
    xphase<2>(v, lo2);
    xphase<1>(v, lo1);
    rmerge(v);
    // merge to 256
    xmirror<31>(v, lo16);
    xphase<8>(v, lo8);
    xphase<4>(v, lo4);
    xphase<2>(v, lo2);
    xphase<1>(v, lo1);
    rmerge(v);

    // ---- neighbor for r=7 (cross-lane, uniform control flow) ----
    float nxt = __shfl(v[0], lane + 1, 64);  // lane31/63 are pads -> don't care

    // ---- sdt ----
    float sg8[8] = { s0.x, s0.y, s0.z, s0.w, s1.x, s1.y, s1.z, s1.w };
    float sdt[8];
    #pragma unroll
    for (int r = 0; r < 8; ++r){
        float tn = (r < 7) ? v[r + 1] : nxt;
        sdt[r] = act ? sg8[r] * (tn - v[r]) : 0.0f;
    }

    // ---- prefix sum: in-lane inclusive over 8, then per-half DPP scan ----
    float pre[8];
    float run = 0.0f;
    #pragma unroll
    for (int r = 0; r < 8; ++r){ run += sdt[r]; pre[r] = run; }
    float x = run;
    x += dpp0<0x111, 0xF>(x);   // row_shr:1
    x += dpp0<0x112, 0xF>(x);   // row_shr:2
    x += dpp0<0x114, 0xF>(x);   // row_shr:4
    x += dpp0<0x118, 0xF>(x);   // row_shr:8
    x += dpp0<0x142, 0xA>(x);   // row_bcast:15 into rows 1,3 (per-half scan)
    float laneExcl = x - run;

    // ---- wi via telescoped exponentials: excl_r == incl_{r-1} -> 9 exps ----
    float wi[8];
    float prev = __expf(-laneExcl);
    #pragma unroll
    for (int r = 0; r < 8; ++r){
        float e = __expf(-(laneExcl + pre[r]));
        wi[r] = prev - e;
        prev = e;
    }
    if (act){
        float* wrow = out + (size_t)RAYS * 3 + (size_t)ray * NS + 8 * sl;
        *reinterpret_cast<float4*>(wrow)     = make_float4(wi[0], wi[1], wi[2], wi[3]);
        *reinterpret_cast<float4*>(wrow + 4) = make_float4(wi[4], wi[5], wi[6], wi[7]);
    }

    // ---- rgb, per-half reduce (wi==0 kills clamped-lane garbage) ----
    float cf[24] = { c0.x,c0.y,c0.z,c0.w, c1.x,c1.y,c1.z,c1.w,
                     c2.x,c2.y,c2.z,c2.w, c3.x,c3.y,c3.z,c3.w,
                     c4.x,c4.y,c4.z,c4.w, c5.x,c5.y,c5.z,c5.w };
    float a0 = 0.f, a1 = 0.f, a2 = 0.f;
    #pragma unroll
    for (int r = 0; r < 8; ++r){
        a0 += wi[r] * cf[3*r + 0];
        a1 += wi[r] * cf[3*r + 1];
        a2 += wi[r] * cf[3*r + 2];
    }
    a0 = halfsum(a0);
    a1 = halfsum(a1);
    a2 = halfsum(a2);
    if (sl < 3){
        float val = (sl == 0) ? a0 : ((sl == 1) ? a1 : a2);
        out[(size_t)ray * 3 + sl] = val;
    }
}

extern "C" void kernel_launch(void* const* d_in, const int* in_sizes, int n_in,
                              void* d_out, int out_size, void* d_ws, size_t ws_size,
                              hipStream_t stream) {
    const float* t     = (const float*)d_in[0];
    const float* sigma = (const float*)d_in[1];
    const float* c     = (const float*)d_in[2];
    float* out = (float*)d_out;
    nerf_integrate<<<RAYS / 8, 256, 0, stream>>>(t, sigma, c, out);
}